// Round 1
// 386.276 us; speedup vs baseline: 1.1312x; 1.1312x over previous
//
#include <hip/hip_runtime.h>
#include <cstdint>

#define KDIM 4096
#define NNODE 4096
#define KSPLIT 2
#define TSTEPS 128            // K-steps of 32 over KDIM
#define THALF (TSTEPS / KSPLIT)

typedef __bf16 bf16x8 __attribute__((ext_vector_type(8)));
typedef float floatx4 __attribute__((ext_vector_type(4)));

__device__ __forceinline__ uint16_t f2b(float f) {
  union { float f; uint32_t u; } v; v.f = f;
  uint32_t u = v.u;
  return (uint16_t)((u + 0x7FFFu + ((u >> 16) & 1u)) >> 16);  // RNE
}
__device__ __forceinline__ float b2f(uint16_t h) {
  union { uint32_t u; float f; } v; v.u = ((uint32_t)h) << 16; return v.f;
}
__device__ __forceinline__ uint32_t pack2(float a, float b) {
  return (uint32_t)f2b(a) | ((uint32_t)f2b(b) << 16);
}

// Fragment layout (both GEMM operands): frag[f16][t][lane][8] where
// elem = M[f16*16 + mr][t*32 + q*8 + j], lane = q*16 + mr.
// A wave's fragment load = base + lane*16B -> one fully-coalesced 1KB dwordx4.

// ---------- supports: fp32 row-major -> bf16 fragment layout ----------
__global__ __launch_bounds__(256) void cvt_supports(
    const float* __restrict__ s0, const float* __restrict__ s1,
    uint16_t* __restrict__ d0, uint16_t* __restrict__ d1) {
  const float* src = blockIdx.z ? s1 : s0;
  uint16_t* dst = blockIdx.z ? d1 : d0;
  const int c16 = blockIdx.x, kb = blockIdx.y;      // 256 x 32
  const int col_in = threadIdx.x >> 4, k8 = threadIdx.x & 15;
  const int col = c16 * 16 + col_in;
  const int k = kb * 128 + k8 * 8;
  const float* p = src + (size_t)col * KDIM + k;
  float4 v0 = *(const float4*)p;
  float4 v1 = *(const float4*)(p + 4);
  uint4 o;
  o.x = pack2(v0.x, v0.y); o.y = pack2(v0.z, v0.w);
  o.z = pack2(v1.x, v1.y); o.w = pack2(v1.z, v1.w);
  size_t off = ((size_t)(c16 * 128 + kb * 4 + (k8 >> 2))) * 512 +
               (size_t)((k8 & 3) * 16 + col_in) * 8;
  *(uint4*)(dst + off) = o;
}

// ---------- X1 (gemm1 A): rows (b,[feats(2);prev(16)]) -> fragment layout ----------
__global__ __launch_bounds__(256) void pack_x1(
    const float* __restrict__ inp, const float* __restrict__ st,
    uint16_t* __restrict__ X1) {
  const int r16 = blockIdx.x, kb = blockIdx.y;      // 72 x 32
  const int row_in = threadIdx.x >> 4, k8 = threadIdx.x & 15;
  const int row = r16 * 16 + row_in;
  const int k = kb * 128 + k8 * 8;
  int b = row / 18, c = row - b * 18;
  const float* p = (c < 2) ? (inp + (size_t)b * 8192 + (size_t)c * 4096 + k)
                           : (st + (size_t)b * 65536 + (size_t)(c - 2) * 4096 + k);
  float4 v0 = *(const float4*)p;
  float4 v1 = *(const float4*)(p + 4);
  uint4 o;
  o.x = pack2(v0.x, v0.y); o.y = pack2(v0.z, v0.w);
  o.z = pack2(v1.x, v1.y); o.w = pack2(v1.z, v1.w);
  size_t off = ((size_t)(r16 * 128 + kb * 4 + (k8 >> 2))) * 512 +
               (size_t)((k8 & 3) * 16 + row_in) * 8;
  *(uint4*)(X1 + off) = o;
}

// direct global->LDS, 16B per lane; LDS dest is wave-uniform base + lane*16
__device__ __forceinline__ void gl_lds16(const uint16_t* g, uint16_t* l) {
  __builtin_amdgcn_global_load_lds(
      (const __attribute__((address_space(1))) uint32_t*)g,
      (__attribute__((address_space(3))) uint32_t*)l, 16, 0, 0);
}

// ---------- LDS-shared fragment GEMM ----------
// C = A * S^T, operands pre-packed in fragment layout. 128x128 tile, 4 waves
// (2x2), 16x16x32 MFMA, split-K=2. Block-level AI = 64 FLOP/B (vs 32 for the
// old per-wave streaming): per K-chunk (BK=64) the block stages 16 A-frags +
// 16 B-frags (32 KB) ONCE via global_load_lds(16B) into a linear LDS buffer
// (fragment layout == consume order: no swizzle needed, ds_read_b128 is
// conflict-free), every fragment is then read by 2 waves from LDS.
// 2-phase double-buffered pipeline (T3-minimum): issue next chunk's loads
// before this chunk's MFMAs; one vmcnt(0)+barrier per chunk. LDS = 64 KB ->
// 2 blocks/CU co-resident for cross-block latency overlap.
template <int MODE>
__global__ __launch_bounds__(256) void gemm_frag(
    const uint16_t* __restrict__ Af, const uint16_t* __restrict__ S0f,
    const uint16_t* __restrict__ S1f, uint16_t* __restrict__ D) {
  constexpr int CPB = (MODE == 1) ? 18 : 16;
  constexpr int OUTC = (MODE == 1) ? 36 : 32;
  constexpr size_t PSTRIDE = (size_t)64 * OUTC * NNODE;
  constexpr int KCH = THALF / 2;   // 32 chunks of BK=64 (2 t-frags)

  __shared__ uint16_t sAB[2][32][512];  // 64 KiB: [buf][frag slot][elems]

  const int lane = threadIdx.x & 63, wave = threadIdx.x >> 6;
  const int wr = wave >> 1, wc = wave & 1;
  const int s = blockIdx.z & 1, ks = blockIdx.z >> 1;
  const uint16_t* __restrict__ Bf = s ? S1f : S0f;
  const int yF = blockIdx.y * 8;   // row-frag base
  const int xF = blockIdx.x * 8;   // col-frag base
  const int tBeg = ks * THALF;

  // staging assignment: waves 0,1 -> A frag-rows 0-3/4-7; waves 2,3 -> B.
  // slot for tile frag-row f, sub-t tt: A = f*2+tt, B = 16 + f*2+tt.
  const bool isB = wave >= 2;
  const int half = wave & 1;
  const uint16_t* Gw = (isB ? Bf : Af) +
      ((size_t)((isB ? xF : yF) + half * 4) * 128 + (size_t)tBeg) * 512 +
      (size_t)lane * 8;
  const int slotw = (isB ? 16 : 0) + half * 8;

  floatx4 acc[4][4];
#pragma unroll
  for (int i = 0; i < 4; ++i)
#pragma unroll
    for (int j = 0; j < 4; ++j) acc[i][j] = (floatx4){0.f, 0.f, 0.f, 0.f};

  auto STAGE = [&](int bi, int c) {
    const uint16_t* gt = Gw + (size_t)c * 1024;  // c*2 t-steps * 512 elems
#pragma unroll
    for (int i = 0; i < 8; ++i) {
      const int fr = i >> 1, tt = i & 1;
      gl_lds16(gt + (size_t)fr * 65536 + (size_t)tt * 512,
               &sAB[bi][slotw + i][0]);
    }
  };

  auto COMPUTE = [&](int bi) {
#pragma unroll
    for (int tt = 0; tt < 2; ++tt) {
      bf16x8 a[4], b[4];
#pragma unroll
      for (int rt = 0; rt < 4; ++rt)
        a[rt] = *(const bf16x8*)&sAB[bi][(wr * 4 + rt) * 2 + tt][lane * 8];
#pragma unroll
      for (int ct = 0; ct < 4; ++ct)
        b[ct] = *(const bf16x8*)&sAB[bi][16 + (wc * 4 + ct) * 2 + tt][lane * 8];
#pragma unroll
      for (int rt = 0; rt < 4; ++rt)
#pragma unroll
        for (int ct = 0; ct < 4; ++ct)
          acc[rt][ct] = __builtin_amdgcn_mfma_f32_16x16x32_bf16(
              a[rt], b[ct], acc[rt][ct], 0, 0, 0);
    }
  };

  STAGE(0, 0);
  int cur = 0;
  for (int c = 0; c < KCH - 1; ++c) {
    __syncthreads();            // cur buffer landed (vmcnt(0) before barrier)
    STAGE(cur ^ 1, c + 1);      // next chunk's loads fly under the MFMAs
    COMPUTE(cur);
    cur ^= 1;
  }
  __syncthreads();
  COMPUTE(cur);

  uint16_t* Dp = D + (size_t)ks * PSTRIDE;
  // epilogue: C/D layout col=lane&15, row=(lane>>4)*4+reg; D row-major bf16
#pragma unroll
  for (int rt = 0; rt < 4; ++rt) {
#pragma unroll
    for (int r = 0; r < 4; ++r) {
      int rowg = yF * 16 + wr * 64 + rt * 16 + (lane >> 4) * 4 + r;
      int b = rowg / CPB, c = rowg - b * CPB;
      int jj;
      if (MODE == 1) jj = (c < 2) ? (2 * s + c) : (4 + 16 * s + (c - 2));
      else jj = 16 * s + c;
      uint16_t* drow = Dp + (size_t)(b * OUTC + jj) * NNODE;
#pragma unroll
      for (int ct = 0; ct < 4; ++ct) {
        int colg = xF * 16 + wc * 64 + ct * 16 + (lane & 15);
        drow[colg] = f2b(acc[rt][ct][r]);
      }
    }
  }
}

// ---------- stage2: r,u gates; X2 = r*prev -> fragment layout via LDS transpose ----------
__global__ __launch_bounds__(256) void stage2(
    const uint16_t* __restrict__ P1, const float* __restrict__ state,
    const float* __restrict__ rk, const float* __restrict__ uk,
    uint16_t* __restrict__ X2f, float* __restrict__ U) {
  constexpr size_t PS = (size_t)64 * 36 * NNODE;
  __shared__ float s_rk[576], s_uk[576];
  __shared__ uint16_t s_x2[16 * 264];  // [k][i], padded stride (264) vs 256
  for (int i = threadIdx.x; i < 576; i += 256) { s_rk[i] = rk[i]; s_uk[i] = uk[i]; }
  __syncthreads();
  const int b = blockIdx.x >> 4, nb = blockIdx.x & 15;
  const int i = threadIdx.x;
  const int n = nb * 256 + i;
  float hs[36];
  const uint16_t* p = P1 + (size_t)b * 36 * NNODE + n;
#pragma unroll
  for (int j = 0; j < 36; ++j)
    hs[j] = b2f(p[(size_t)j * NNODE]) + b2f(p[PS + (size_t)j * NNODE]);
  float ar[16], au[16];
#pragma unroll
  for (int k = 0; k < 16; ++k) { ar[k] = 0.f; au[k] = 0.f; }
#pragma unroll
  for (int j = 0; j < 36; ++j) {
    float h = hs[j];
#pragma unroll
    for (int k = 0; k < 16; ++k) {
      ar[k] += h * s_rk[j * 16 + k];
      au[k] += h * s_uk[j * 16 + k];
    }
  }
  const float* sp = state + (size_t)b * 65536 + n;
#pragma unroll
  for (int k = 0; k < 16; ++k) {
    float r = 1.f / (1.f + __expf(-ar[k]));
    float uu = 1.f / (1.f + __expf(-au[k]));
    float prev = sp[(size_t)k * NNODE];
    s_x2[k * 264 + i] = f2b(r * prev);
    U[(size_t)(b * 16 + k) * NNODE + n] = uu;
  }
  __syncthreads();
  // flush 4096 bf16 (16 k x 256 n) to fragment layout: contiguous 8KB region.
  // global o = tl*512 + (qq*16+kk)*8 + jj ; element = (row b*16+kk, n nb*256 + tl*32+qq*8+jj)
  uint16_t* region = X2f + ((size_t)b * 128 + nb * 8) * 512;
#pragma unroll
  for (int rr = 0; rr < 2; ++rr) {
    int fid = rr * 256 + i;
    int kk = fid & 15, qq = (fid >> 4) & 3, tl = fid >> 6;
    uint4 v = *(const uint4*)&s_x2[kk * 264 + tl * 32 + qq * 8];
    *(uint4*)(region + (size_t)fid * 8) = v;
  }
}

// ---------- stage4: c = tanh([h;D3]*ck); z = u*prev + (1-u)*c ----------
// OUTPUT LAYOUT: z is (B, N, U) reshaped -> out[b*65536 + n*16 + k]
__global__ __launch_bounds__(256) void stage4(
    const uint16_t* __restrict__ P1, const uint16_t* __restrict__ P3,
    const float* __restrict__ U, const float* __restrict__ state,
    const float* __restrict__ ck, float* __restrict__ out) {
  constexpr size_t PS1 = (size_t)64 * 36 * NNODE;
  constexpr size_t PS3 = (size_t)64 * 32 * NNODE;
  __shared__ float s_ck[576];
  for (int i = threadIdx.x; i < 576; i += 256) s_ck[i] = ck[i];
  __syncthreads();
  int idx = blockIdx.x * 256 + threadIdx.x;
  int b = idx >> 12, n = idx & 4095;
  float hv[36];
  const uint16_t* p1 = P1 + (size_t)b * 36 * NNODE + n;
#pragma unroll
  for (int j = 0; j < 4; ++j)
    hv[j] = b2f(p1[(size_t)j * NNODE]) + b2f(p1[PS1 + (size_t)j * NNODE]);
  const uint16_t* p3 = P3 + (size_t)b * 32 * NNODE + n;
#pragma unroll
  for (int j = 0; j < 32; ++j)
    hv[4 + j] = b2f(p3[(size_t)j * NNODE]) + b2f(p3[PS3 + (size_t)j * NNODE]);
  float ac[16];
#pragma unroll
  for (int k = 0; k < 16; ++k) ac[k] = 0.f;
#pragma unroll
  for (int j = 0; j < 36; ++j) {
    float h = hv[j];
#pragma unroll
    for (int k = 0; k < 16; ++k) ac[k] += h * s_ck[j * 16 + k];
  }
  const float* sp = state + (size_t)b * 65536 + n;
  const float* up = U + (size_t)b * 16 * NNODE + n;
  float z[16];
#pragma unroll
  for (int k = 0; k < 16; ++k) {
    float e = __expf(2.f * ac[k]);
    float c = 1.f - 2.f / (e + 1.f);  // tanh, saturates at +/-inf
    float uu = up[(size_t)k * NNODE];
    float prev = sp[(size_t)k * NNODE];
    z[k] = uu * prev + (1.f - uu) * c;
  }
  float4* po = (float4*)(out + (size_t)b * 65536 + (size_t)n * 16);
#pragma unroll
  for (int k4 = 0; k4 < 4; ++k4)
    po[k4] = make_float4(z[k4 * 4], z[k4 * 4 + 1], z[k4 * 4 + 2], z[k4 * 4 + 3]);
}

extern "C" void kernel_launch(void* const* d_in, const int* in_sizes, int n_in,
                              void* d_out, int out_size, void* d_ws, size_t ws_size,
                              hipStream_t stream) {
  const float* inputs = (const float*)d_in[0];
  const float* state = (const float*)d_in[1];
  const float* s0 = (const float*)d_in[2];
  const float* s1 = (const float*)d_in[3];
  const float* rk = (const float*)d_in[4];
  const float* uk = (const float*)d_in[5];
  const float* ck = (const float*)d_in[6];
  float* out = (float*)d_out;
  char* ws = (char*)d_ws;

  // workspace layout (bytes); X2f aliases X1f (dead after gemm1)
  uint16_t* S0f = (uint16_t*)(ws);                  // 33,554,432
  uint16_t* S1f = (uint16_t*)(ws + 33554432);       // 33,554,432
  uint16_t* X1f = (uint16_t*)(ws + 67108864);       // 9,437,184   (1152 x 4096 bf16, frag)
  uint16_t* X2f = (uint16_t*)(ws + 67108864);       // 8,388,608   (aliases X1f, frag)
  uint16_t* P1 = (uint16_t*)(ws + 76546048);        // 2 x 18,874,368 (split-K partials)
  float* U = (float*)(ws + 114294784);              // 16,777,216
  uint16_t* P3 = (uint16_t*)(ws + 131072000);       // 2 x 16,777,216 (split-K partials)
  // total 164,626,432 bytes

  cvt_supports<<<dim3(256, 32, 2), 256, 0, stream>>>(s0, s1, S0f, S1f);
  pack_x1<<<dim3(72, 32), 256, 0, stream>>>(inputs, state, X1f);
  gemm_frag<1><<<dim3(32, 9, 2 * KSPLIT), 256, 0, stream>>>(X1f, S0f, S1f, P1);
  stage2<<<1024, 256, 0, stream>>>(P1, state, rk, uk, X2f, U);
  gemm_frag<3><<<dim3(32, 8, 2 * KSPLIT), 256, 0, stream>>>(X2f, S0f, S1f, P3);
  stage4<<<1024, 256, 0, stream>>>(P1, P3, U, state, ck, out);
}

// Round 2
// 365.389 us; speedup vs baseline: 1.1958x; 1.0572x over previous
//
#include <hip/hip_runtime.h>
#include <cstdint>

#define KDIM 4096
#define NNODE 4096
#define KSPLIT 2
#define TSTEPS 128            // K-steps of 32 over KDIM
#define THALF (TSTEPS / KSPLIT)

typedef __bf16 bf16x8 __attribute__((ext_vector_type(8)));
typedef float floatx4 __attribute__((ext_vector_type(4)));

__device__ __forceinline__ uint16_t f2b(float f) {
  union { float f; uint32_t u; } v; v.f = f;
  uint32_t u = v.u;
  return (uint16_t)((u + 0x7FFFu + ((u >> 16) & 1u)) >> 16);  // RNE
}
__device__ __forceinline__ float b2f(uint16_t h) {
  union { uint32_t u; float f; } v; v.u = ((uint32_t)h) << 16; return v.f;
}
__device__ __forceinline__ uint32_t pack2(float a, float b) {
  return (uint32_t)f2b(a) | ((uint32_t)f2b(b) << 16);
}

// Fragment layout (both GEMM operands): frag[f16][t][lane][8] where
// elem = M[f16*16 + mr][t*32 + q*8 + j], lane = q*16 + mr.
// A wave's fragment load = base + lane*16B -> one fully-coalesced 1KB dwordx4.

// ---------- supports: fp32 row-major -> bf16 fragment layout ----------
__global__ __launch_bounds__(256) void cvt_supports(
    const float* __restrict__ s0, const float* __restrict__ s1,
    uint16_t* __restrict__ d0, uint16_t* __restrict__ d1) {
  const float* src = blockIdx.z ? s1 : s0;
  uint16_t* dst = blockIdx.z ? d1 : d0;
  const int c16 = blockIdx.x, kb = blockIdx.y;      // 256 x 32
  const int col_in = threadIdx.x >> 4, k8 = threadIdx.x & 15;
  const int col = c16 * 16 + col_in;
  const int k = kb * 128 + k8 * 8;
  const float* p = src + (size_t)col * KDIM + k;
  float4 v0 = *(const float4*)p;
  float4 v1 = *(const float4*)(p + 4);
  uint4 o;
  o.x = pack2(v0.x, v0.y); o.y = pack2(v0.z, v0.w);
  o.z = pack2(v1.x, v1.y); o.w = pack2(v1.z, v1.w);
  size_t off = ((size_t)(c16 * 128 + kb * 4 + (k8 >> 2))) * 512 +
               (size_t)((k8 & 3) * 16 + col_in) * 8;
  *(uint4*)(dst + off) = o;
}

// ---------- X1 (gemm1 A): rows (b,[feats(2);prev(16)]) -> fragment layout ----------
__global__ __launch_bounds__(256) void pack_x1(
    const float* __restrict__ inp, const float* __restrict__ st,
    uint16_t* __restrict__ X1) {
  const int r16 = blockIdx.x, kb = blockIdx.y;      // 72 x 32
  const int row_in = threadIdx.x >> 4, k8 = threadIdx.x & 15;
  const int row = r16 * 16 + row_in;
  const int k = kb * 128 + k8 * 8;
  int b = row / 18, c = row - b * 18;
  const float* p = (c < 2) ? (inp + (size_t)b * 8192 + (size_t)c * 4096 + k)
                           : (st + (size_t)b * 65536 + (size_t)(c - 2) * 4096 + k);
  float4 v0 = *(const float4*)p;
  float4 v1 = *(const float4*)(p + 4);
  uint4 o;
  o.x = pack2(v0.x, v0.y); o.y = pack2(v0.z, v0.w);
  o.z = pack2(v1.x, v1.y); o.w = pack2(v1.z, v1.w);
  size_t off = ((size_t)(r16 * 128 + kb * 4 + (k8 >> 2))) * 512 +
               (size_t)((k8 & 3) * 16 + row_in) * 8;
  *(uint4*)(X1 + off) = o;
}

// direct global->LDS, 16B per lane; LDS dest is wave-uniform base + lane*16
__device__ __forceinline__ void gl_lds16(const uint16_t* g, uint16_t* l) {
  __builtin_amdgcn_global_load_lds(
      (const __attribute__((address_space(1))) uint32_t*)g,
      (__attribute__((address_space(3))) uint32_t*)l, 16, 0, 0);
}

// ---------- depth-3 counted-vmcnt LDS-shared fragment GEMM (T3+T4+T5) ----------
// C = A * S^T, operands pre-packed in fragment layout. 128x128 tile, 4 waves
// (2x2), 16x16x32 MFMA, split-K=2. K-chunks of 32 (16 frags = 16 KiB), FOUR
// LDS buffers (64 KiB total -> 2 blocks/CU). Per iter c:
//   STAGE chunk c+2 into buf[(c+2)&3]      (4 global_load_lds per wave)
//   s_waitcnt vmcnt(8)                     (chunk c landed; c+1,c+2 IN FLIGHT)
//   s_barrier                              (raw: no drain-to-zero!)
//   ds_read + 16 MFMA (setprio 1)
// Safety: buf[(c+2)&3] was last read at iter c-2; iter c-1's barrier orders
// every wave's reads before any wave's iter-c stage (BUFS = depth+1 => one
// barrier per chunk suffices). Clamped redundant tail stages keep the vmcnt
// immediate constant. Loads now have ~2 phases + cross-block overlap to land
// (R1 post-mortem: the __syncthreads vmcnt(0) drain, ~200-600cy/iter, was the
// wall -> MfmaUtil 32%).
template <int MODE>
__global__ __launch_bounds__(256) void gemm_frag(
    const uint16_t* __restrict__ Af, const uint16_t* __restrict__ S0f,
    const uint16_t* __restrict__ S1f, uint16_t* __restrict__ D) {
  constexpr int CPB = (MODE == 1) ? 18 : 16;
  constexpr int OUTC = (MODE == 1) ? 36 : 32;
  constexpr size_t PSTRIDE = (size_t)64 * OUTC * NNODE;
  constexpr int NCH = THALF;       // 64 chunks of K=32

  __shared__ uint16_t sAB[4][16][512];  // 64 KiB: [buf][frag slot][elems]

  const int lane = threadIdx.x & 63, wave = threadIdx.x >> 6;
  const int wr = wave >> 1, wc = wave & 1;
  const int s = blockIdx.z & 1, ks = blockIdx.z >> 1;
  const uint16_t* __restrict__ Bf = s ? S1f : S0f;
  const int yF = blockIdx.y * 8;   // row-frag base
  const int xF = blockIdx.x * 8;   // col-frag base
  const int tBeg = ks * THALF;

  // staging: wave w stages 4 frags/chunk. w 0,1 -> A frag-rows 0-3 / 4-7;
  // w 2,3 -> B frag-cols 0-3 / 4-7. slot: A frag f -> f, B frag g -> 8+g.
  const bool isB = wave >= 2;
  const int fbase = (wave & 1) * 4;
  const uint16_t* Gw = (isB ? Bf : Af) +
      ((size_t)((isB ? xF : yF) + fbase) * 128 + (size_t)tBeg) * 512 +
      (size_t)lane * 8;
  const int slotw = (isB ? 8 : 0) + fbase;

  floatx4 acc[4][4];
#pragma unroll
  for (int i = 0; i < 4; ++i)
#pragma unroll
    for (int j = 0; j < 4; ++j) acc[i][j] = (floatx4){0.f, 0.f, 0.f, 0.f};

  auto STAGE = [&](int bi, int c) {
    const uint16_t* gt = Gw + (size_t)c * 512;
#pragma unroll
    for (int i = 0; i < 4; ++i)
      gl_lds16(gt + (size_t)i * 65536, &sAB[bi][slotw + i][0]);
  };

  // prologue: chunks 0,1 in flight
  STAGE(0, 0);
  STAGE(1, 1);

  for (int c = 0; c < NCH; ++c) {
    int cl = c + 2; if (cl > NCH - 1) cl = NCH - 1;  // clamped tail (redundant)
    STAGE((c + 2) & 3, cl);
    asm volatile("s_waitcnt vmcnt(8)" ::: "memory");
    __builtin_amdgcn_sched_barrier(0);
    __builtin_amdgcn_s_barrier();
    __builtin_amdgcn_sched_barrier(0);
    const int bi = c & 3;
    bf16x8 a[4], b[4];
#pragma unroll
    for (int rt = 0; rt < 4; ++rt)
      a[rt] = *(const bf16x8*)&sAB[bi][wr * 4 + rt][lane * 8];
#pragma unroll
    for (int ct = 0; ct < 4; ++ct)
      b[ct] = *(const bf16x8*)&sAB[bi][8 + wc * 4 + ct][lane * 8];
    __builtin_amdgcn_s_setprio(1);
#pragma unroll
    for (int rt = 0; rt < 4; ++rt)
#pragma unroll
      for (int ct = 0; ct < 4; ++ct)
        acc[rt][ct] = __builtin_amdgcn_mfma_f32_16x16x32_bf16(
            a[rt], b[ct], acc[rt][ct], 0, 0, 0);
    __builtin_amdgcn_s_setprio(0);
    __builtin_amdgcn_sched_barrier(0);
  }

  uint16_t* Dp = D + (size_t)ks * PSTRIDE;
  // epilogue: C/D layout col=lane&15, row=(lane>>4)*4+reg; D row-major bf16
#pragma unroll
  for (int rt = 0; rt < 4; ++rt) {
#pragma unroll
    for (int r = 0; r < 4; ++r) {
      int rowg = yF * 16 + wr * 64 + rt * 16 + (lane >> 4) * 4 + r;
      int b = rowg / CPB, c = rowg - b * CPB;
      int jj;
      if (MODE == 1) jj = (c < 2) ? (2 * s + c) : (4 + 16 * s + (c - 2));
      else jj = 16 * s + c;
      uint16_t* drow = Dp + (size_t)(b * OUTC + jj) * NNODE;
#pragma unroll
      for (int ct = 0; ct < 4; ++ct) {
        int colg = xF * 16 + wc * 64 + ct * 16 + (lane & 15);
        drow[colg] = f2b(acc[rt][ct][r]);
      }
    }
  }
}

// ---------- stage2: r,u gates; X2 = r*prev -> fragment layout via LDS transpose ----------
__global__ __launch_bounds__(256) void stage2(
    const uint16_t* __restrict__ P1, const float* __restrict__ state,
    const float* __restrict__ rk, const float* __restrict__ uk,
    uint16_t* __restrict__ X2f, float* __restrict__ U) {
  constexpr size_t PS = (size_t)64 * 36 * NNODE;
  __shared__ float s_rk[576], s_uk[576];
  __shared__ uint16_t s_x2[16 * 264];  // [k][i], padded stride (264) vs 256
  for (int i = threadIdx.x; i < 576; i += 256) { s_rk[i] = rk[i]; s_uk[i] = uk[i]; }
  __syncthreads();
  const int b = blockIdx.x >> 4, nb = blockIdx.x & 15;
  const int i = threadIdx.x;
  const int n = nb * 256 + i;
  float hs[36];
  const uint16_t* p = P1 + (size_t)b * 36 * NNODE + n;
#pragma unroll
  for (int j = 0; j < 36; ++j)
    hs[j] = b2f(p[(size_t)j * NNODE]) + b2f(p[PS + (size_t)j * NNODE]);
  float ar[16], au[16];
#pragma unroll
  for (int k = 0; k < 16; ++k) { ar[k] = 0.f; au[k] = 0.f; }
#pragma unroll
  for (int j = 0; j < 36; ++j) {
    float h = hs[j];
#pragma unroll
    for (int k = 0; k < 16; ++k) {
      ar[k] += h * s_rk[j * 16 + k];
      au[k] += h * s_uk[j * 16 + k];
    }
  }
  const float* sp = state + (size_t)b * 65536 + n;
#pragma unroll
  for (int k = 0; k < 16; ++k) {
    float r = 1.f / (1.f + __expf(-ar[k]));
    float uu = 1.f / (1.f + __expf(-au[k]));
    float prev = sp[(size_t)k * NNODE];
    s_x2[k * 264 + i] = f2b(r * prev);
    U[(size_t)(b * 16 + k) * NNODE + n] = uu;
  }
  __syncthreads();
  // flush 4096 bf16 (16 k x 256 n) to fragment layout: contiguous 8KB region.
  // global o = tl*512 + (qq*16+kk)*8 + jj ; element = (row b*16+kk, n nb*256 + tl*32+qq*8+jj)
  uint16_t* region = X2f + ((size_t)b * 128 + nb * 8) * 512;
#pragma unroll
  for (int rr = 0; rr < 2; ++rr) {
    int fid = rr * 256 + i;
    int kk = fid & 15, qq = (fid >> 4) & 3, tl = fid >> 6;
    uint4 v = *(const uint4*)&s_x2[kk * 264 + tl * 32 + qq * 8];
    *(uint4*)(region + (size_t)fid * 8) = v;
  }
}

// ---------- stage4: c = tanh([h;D3]*ck); z = u*prev + (1-u)*c ----------
// OUTPUT LAYOUT: z is (B, N, U) reshaped -> out[b*65536 + n*16 + k]
__global__ __launch_bounds__(256) void stage4(
    const uint16_t* __restrict__ P1, const uint16_t* __restrict__ P3,
    const float* __restrict__ U, const float* __restrict__ state,
    const float* __restrict__ ck, float* __restrict__ out) {
  constexpr size_t PS1 = (size_t)64 * 36 * NNODE;
  constexpr size_t PS3 = (size_t)64 * 32 * NNODE;
  __shared__ float s_ck[576];
  for (int i = threadIdx.x; i < 576; i += 256) s_ck[i] = ck[i];
  __syncthreads();
  int idx = blockIdx.x * 256 + threadIdx.x;
  int b = idx >> 12, n = idx & 4095;
  float hv[36];
  const uint16_t* p1 = P1 + (size_t)b * 36 * NNODE + n;
#pragma unroll
  for (int j = 0; j < 4; ++j)
    hv[j] = b2f(p1[(size_t)j * NNODE]) + b2f(p1[PS1 + (size_t)j * NNODE]);
  const uint16_t* p3 = P3 + (size_t)b * 32 * NNODE + n;
#pragma unroll
  for (int j = 0; j < 32; ++j)
    hv[4 + j] = b2f(p3[(size_t)j * NNODE]) + b2f(p3[PS3 + (size_t)j * NNODE]);
  float ac[16];
#pragma unroll
  for (int k = 0; k < 16; ++k) ac[k] = 0.f;
#pragma unroll
  for (int j = 0; j < 36; ++j) {
    float h = hv[j];
#pragma unroll
    for (int k = 0; k < 16; ++k) ac[k] += h * s_ck[j * 16 + k];
  }
  const float* sp = state + (size_t)b * 65536 + n;
  const float* up = U + (size_t)b * 16 * NNODE + n;
  float z[16];
#pragma unroll
  for (int k = 0; k < 16; ++k) {
    float e = __expf(2.f * ac[k]);
    float c = 1.f - 2.f / (e + 1.f);  // tanh, saturates at +/-inf
    float uu = up[(size_t)k * NNODE];
    float prev = sp[(size_t)k * NNODE];
    z[k] = uu * prev + (1.f - uu) * c;
  }
  float4* po = (float4*)(out + (size_t)b * 65536 + (size_t)n * 16);
#pragma unroll
  for (int k4 = 0; k4 < 4; ++k4)
    po[k4] = make_float4(z[k4 * 4], z[k4 * 4 + 1], z[k4 * 4 + 2], z[k4 * 4 + 3]);
}

extern "C" void kernel_launch(void* const* d_in, const int* in_sizes, int n_in,
                              void* d_out, int out_size, void* d_ws, size_t ws_size,
                              hipStream_t stream) {
  const float* inputs = (const float*)d_in[0];
  const float* state = (const float*)d_in[1];
  const float* s0 = (const float*)d_in[2];
  const float* s1 = (const float*)d_in[3];
  const float* rk = (const float*)d_in[4];
  const float* uk = (const float*)d_in[5];
  const float* ck = (const float*)d_in[6];
  float* out = (float*)d_out;
  char* ws = (char*)d_ws;

  // workspace layout (bytes); X2f aliases X1f (dead after gemm1)
  uint16_t* S0f = (uint16_t*)(ws);                  // 33,554,432
  uint16_t* S1f = (uint16_t*)(ws + 33554432);       // 33,554,432
  uint16_t* X1f = (uint16_t*)(ws + 67108864);       // 9,437,184   (1152 x 4096 bf16, frag)
  uint16_t* X2f = (uint16_t*)(ws + 67108864);       // 8,388,608   (aliases X1f, frag)
  uint16_t* P1 = (uint16_t*)(ws + 76546048);        // 2 x 18,874,368 (split-K partials)
  float* U = (float*)(ws + 114294784);              // 16,777,216
  uint16_t* P3 = (uint16_t*)(ws + 131072000);       // 2 x 16,777,216 (split-K partials)
  // total 164,626,432 bytes

  cvt_supports<<<dim3(256, 32, 2), 256, 0, stream>>>(s0, s1, S0f, S1f);
  pack_x1<<<dim3(72, 32), 256, 0, stream>>>(inputs, state, X1f);
  gemm_frag<1><<<dim3(32, 9, 2 * KSPLIT), 256, 0, stream>>>(X1f, S0f, S1f, P1);
  stage2<<<1024, 256, 0, stream>>>(P1, state, rk, uk, X2f, U);
  gemm_frag<3><<<dim3(32, 8, 2 * KSPLIT), 256, 0, stream>>>(X2f, S0f, S1f, P3);
  stage4<<<1024, 256, 0, stream>>>(P1, P3, U, state, ck, out);
}

// Round 3
// 352.519 us; speedup vs baseline: 1.2395x; 1.0365x over previous
//
#include <hip/hip_runtime.h>
#include <cstdint>

#define KDIM 4096
#define NNODE 4096
#define KSPLIT 2
#define TSTEPS 128            // K-steps of 32 over KDIM
#define THALF (TSTEPS / KSPLIT)

typedef __bf16 bf16x8 __attribute__((ext_vector_type(8)));
typedef float floatx4 __attribute__((ext_vector_type(4)));

__device__ __forceinline__ uint16_t f2b(float f) {
  union { float f; uint32_t u; } v; v.f = f;
  uint32_t u = v.u;
  return (uint16_t)((u + 0x7FFFu + ((u >> 16) & 1u)) >> 16);  // RNE
}
__device__ __forceinline__ float b2f(uint16_t h) {
  union { uint32_t u; float f; } v; v.u = ((uint32_t)h) << 16; return v.f;
}
__device__ __forceinline__ uint32_t pack2(float a, float b) {
  return (uint32_t)f2b(a) | ((uint32_t)f2b(b) << 16);
}

// Fragment layout (both GEMM operands): frag[f16][t][lane][8] where
// elem = M[f16*16 + mr][t*32 + q*8 + j], lane = q*16 + mr.
// A wave's fragment load = base + lane*16B -> one fully-coalesced 1KB dwordx4.

// ---------- supports: fp32 row-major -> bf16 fragment layout ----------
__global__ __launch_bounds__(256) void cvt_supports(
    const float* __restrict__ s0, const float* __restrict__ s1,
    uint16_t* __restrict__ d0, uint16_t* __restrict__ d1) {
  const float* src = blockIdx.z ? s1 : s0;
  uint16_t* dst = blockIdx.z ? d1 : d0;
  const int c16 = blockIdx.x, kb = blockIdx.y;      // 256 x 32
  const int col_in = threadIdx.x >> 4, k8 = threadIdx.x & 15;
  const int col = c16 * 16 + col_in;
  const int k = kb * 128 + k8 * 8;
  const float* p = src + (size_t)col * KDIM + k;
  float4 v0 = *(const float4*)p;
  float4 v1 = *(const float4*)(p + 4);
  uint4 o;
  o.x = pack2(v0.x, v0.y); o.y = pack2(v0.z, v0.w);
  o.z = pack2(v1.x, v1.y); o.w = pack2(v1.z, v1.w);
  size_t off = ((size_t)(c16 * 128 + kb * 4 + (k8 >> 2))) * 512 +
               (size_t)((k8 & 3) * 16 + col_in) * 8;
  *(uint4*)(dst + off) = o;
}

// ---------- X1 (gemm1 A): rows (b,[feats(2);prev(16)]) -> fragment layout ----------
__global__ __launch_bounds__(256) void pack_x1(
    const float* __restrict__ inp, const float* __restrict__ st,
    uint16_t* __restrict__ X1) {
  const int r16 = blockIdx.x, kb = blockIdx.y;      // 72 x 32
  const int row_in = threadIdx.x >> 4, k8 = threadIdx.x & 15;
  const int row = r16 * 16 + row_in;
  const int k = kb * 128 + k8 * 8;
  int b = row / 18, c = row - b * 18;
  const float* p = (c < 2) ? (inp + (size_t)b * 8192 + (size_t)c * 4096 + k)
                           : (st + (size_t)b * 65536 + (size_t)(c - 2) * 4096 + k);
  float4 v0 = *(const float4*)p;
  float4 v1 = *(const float4*)(p + 4);
  uint4 o;
  o.x = pack2(v0.x, v0.y); o.y = pack2(v0.z, v0.w);
  o.z = pack2(v1.x, v1.y); o.w = pack2(v1.z, v1.w);
  size_t off = ((size_t)(r16 * 128 + kb * 4 + (k8 >> 2))) * 512 +
               (size_t)((k8 & 3) * 16 + row_in) * 8;
  *(uint4*)(X1 + off) = o;
}

// direct global->LDS, 16B per lane; LDS dest is wave-uniform base + lane*16
__device__ __forceinline__ void gl_lds16(const uint16_t* g, uint16_t* l) {
  __builtin_amdgcn_global_load_lds(
      (const __attribute__((address_space(1))) uint32_t*)g,
      (__attribute__((address_space(3))) uint32_t*)l, 16, 0, 0);
}

// ---------- depth-3 counted-vmcnt + register-double-buffered GEMM ----------
// C = A * S^T, operands pre-packed in fragment layout. 128x128 tile, 4 waves
// (2x2), 16x16x32 MFMA, split-K=2. K-chunks of 32 (16 frags = 16 KiB), FOUR
// LDS buffers (64 KiB -> 2 blocks/CU). R2 post-mortem: MfmaUtil stuck at 39%
// because each iter's ds_read(8)+lgkmcnt(0)+MFMA(16) was serial per wave and
// barrier-lockstep across the block -> ~600cy exposed LDS issue+latency.
// R3: REGISTER double-buffer. Iter c:
//   STAGE chunk c+3 -> buf[(c+3)&3]    (4 gl_lds/wave; c+1..c+3 in flight)
//   s_waitcnt vmcnt(8)                 (chunk c+1 LANDED; c+2,c+3 in flight)
//   s_barrier                          (raw, no drain)
//   ds_read chunk c+1 -> regset NEXT   (8 ds_read_b128, no wait)
//   s_waitcnt lgkmcnt(8)               (regset CUR's reads -- issued LAST
//                                       iter, ~700cy ago -- complete)
//   16 MFMA on regset CUR (setprio 1)
// MFMA never waits on same-iter ds_reads; LDS pipe overlaps MFMA pipe.
// Buffer safety: staged buf's old chunk was read (into regs) at iter c-2;
// barrier at c-1 intervenes. Loop unrolled x4 (static buf idx) with named
// A/B reg sets (rule #20); sched_barrier(0) after counted waits (rule #18).
template <int MODE>
__global__ __launch_bounds__(256, 2) void gemm_frag(
    const uint16_t* __restrict__ Af, const uint16_t* __restrict__ S0f,
    const uint16_t* __restrict__ S1f, uint16_t* __restrict__ D) {
  constexpr int CPB = (MODE == 1) ? 18 : 16;
  constexpr int OUTC = (MODE == 1) ? 36 : 32;
  constexpr size_t PSTRIDE = (size_t)64 * OUTC * NNODE;
  constexpr int NCH = THALF;       // 64 chunks of K=32

  __shared__ uint16_t sAB[4][16][512];  // 64 KiB: [buf][frag slot][elems]

  const int lane = threadIdx.x & 63, wave = threadIdx.x >> 6;
  const int wr = wave >> 1, wc = wave & 1;
  const int s = blockIdx.z & 1, ks = blockIdx.z >> 1;
  const uint16_t* __restrict__ Bf = s ? S1f : S0f;
  const int yF = blockIdx.y * 8;   // row-frag base
  const int xF = blockIdx.x * 8;   // col-frag base
  const int tBeg = ks * THALF;

  // staging: wave w stages 4 frags/chunk. w 0,1 -> A frag-rows 0-3 / 4-7;
  // w 2,3 -> B frag-cols 0-3 / 4-7. slot: A frag f -> f, B frag g -> 8+g.
  const bool isB = wave >= 2;
  const int fbase = (wave & 1) * 4;
  const uint16_t* Gw = (isB ? Bf : Af) +
      ((size_t)((isB ? xF : yF) + fbase) * 128 + (size_t)tBeg) * 512 +
      (size_t)lane * 8;
  const int slotw = (isB ? 8 : 0) + fbase;

  floatx4 acc[4][4];
#pragma unroll
  for (int i = 0; i < 4; ++i)
#pragma unroll
    for (int j = 0; j < 4; ++j) acc[i][j] = (floatx4){0.f, 0.f, 0.f, 0.f};

  auto STAGE = [&](int bi, int c) {
    const uint16_t* gt = Gw + (size_t)c * 512;
#pragma unroll
    for (int i = 0; i < 4; ++i)
      gl_lds16(gt + (size_t)i * 65536, &sAB[bi][slotw + i][0]);
  };

  auto LDREG = [&](int bi, bf16x8* a, bf16x8* b) {
#pragma unroll
    for (int rt = 0; rt < 4; ++rt)
      a[rt] = *(const bf16x8*)&sAB[bi][wr * 4 + rt][lane * 8];
#pragma unroll
    for (int ct = 0; ct < 4; ++ct)
      b[ct] = *(const bf16x8*)&sAB[bi][8 + wc * 4 + ct][lane * 8];
  };

  auto MFMA16 = [&](bf16x8* a, bf16x8* b) {
    __builtin_amdgcn_s_setprio(1);
#pragma unroll
    for (int rt = 0; rt < 4; ++rt)
#pragma unroll
      for (int ct = 0; ct < 4; ++ct)
        acc[rt][ct] = __builtin_amdgcn_mfma_f32_16x16x32_bf16(
            a[rt], b[ct], acc[rt][ct], 0, 0, 0);
    __builtin_amdgcn_s_setprio(0);
  };

  // prologue: chunks 0,1,2 in flight; preload chunk 0 into regset A
  STAGE(0, 0);
  STAGE(1, 1);
  STAGE(2, 2);
  asm volatile("s_waitcnt vmcnt(8)" ::: "memory");   // chunk 0 landed
  __builtin_amdgcn_sched_barrier(0);
  __builtin_amdgcn_s_barrier();
  __builtin_amdgcn_sched_barrier(0);
  bf16x8 aA[4], bA[4], aB[4], bB[4];
  LDREG(0, aA, bA);

  // body: c = 4m+j; read buf (c+1)&3 into NEXT set, MFMA CUR set.
#define GEMM_ITER(J, RDBUF, STBUF, CURA, CURB, NXTA, NXTB)                  \
  {                                                                         \
    int cl = c0 + 3 + (J);                                                  \
    if (cl > NCH - 1) cl = NCH - 1; /* clamped redundant tail stage */      \
    STAGE((STBUF), cl);                                                     \
    asm volatile("s_waitcnt vmcnt(8)" ::: "memory");                        \
    __builtin_amdgcn_sched_barrier(0);                                      \
    __builtin_amdgcn_s_barrier();                                           \
    __builtin_amdgcn_sched_barrier(0);                                      \
    LDREG((RDBUF), NXTA, NXTB);                                             \
    asm volatile("s_waitcnt lgkmcnt(8)" ::: "memory");                      \
    __builtin_amdgcn_sched_barrier(0);                                      \
    MFMA16(CURA, CURB);                                                     \
    __builtin_amdgcn_sched_barrier(0);                                      \
  }

  for (int m = 0; m < NCH / 4; ++m) {
    const int c0 = m * 4;
    GEMM_ITER(0, 1, 3, aA, bA, aB, bB)   // c=c0+0: MFMA chunk c0   (A), load c0+1 -> B
    GEMM_ITER(1, 2, 0, aB, bB, aA, bA)   // c=c0+1: MFMA chunk c0+1 (B), load c0+2 -> A
    GEMM_ITER(2, 3, 1, aA, bA, aB, bB)   // c=c0+2
    GEMM_ITER(3, 0, 2, aB, bB, aA, bA)   // c=c0+3 (last m: redundant load, unused)
  }
#undef GEMM_ITER

  uint16_t* Dp = D + (size_t)ks * PSTRIDE;
  // epilogue: C/D layout col=lane&15, row=(lane>>4)*4+reg; D row-major bf16
#pragma unroll
  for (int rt = 0; rt < 4; ++rt) {
#pragma unroll
    for (int r = 0; r < 4; ++r) {
      int rowg = yF * 16 + wr * 64 + rt * 16 + (lane >> 4) * 4 + r;
      int b = rowg / CPB, c = rowg - b * CPB;
      int jj;
      if (MODE == 1) jj = (c < 2) ? (2 * s + c) : (4 + 16 * s + (c - 2));
      else jj = 16 * s + c;
      uint16_t* drow = Dp + (size_t)(b * OUTC + jj) * NNODE;
#pragma unroll
      for (int ct = 0; ct < 4; ++ct) {
        int colg = xF * 16 + wc * 64 + ct * 16 + (lane & 15);
        drow[colg] = f2b(acc[rt][ct][r]);
      }
    }
  }
}

// ---------- stage2: r,u gates; X2 = r*prev -> fragment layout via LDS transpose ----------
__global__ __launch_bounds__(256) void stage2(
    const uint16_t* __restrict__ P1, const float* __restrict__ state,
    const float* __restrict__ rk, const float* __restrict__ uk,
    uint16_t* __restrict__ X2f, float* __restrict__ U) {
  constexpr size_t PS = (size_t)64 * 36 * NNODE;
  __shared__ float s_rk[576], s_uk[576];
  __shared__ uint16_t s_x2[16 * 264];  // [k][i], padded stride (264) vs 256
  for (int i = threadIdx.x; i < 576; i += 256) { s_rk[i] = rk[i]; s_uk[i] = uk[i]; }
  __syncthreads();
  const int b = blockIdx.x >> 4, nb = blockIdx.x & 15;
  const int i = threadIdx.x;
  const int n = nb * 256 + i;
  float hs[36];
  const uint16_t* p = P1 + (size_t)b * 36 * NNODE + n;
#pragma unroll
  for (int j = 0; j < 36; ++j)
    hs[j] = b2f(p[(size_t)j * NNODE]) + b2f(p[PS + (size_t)j * NNODE]);
  float ar[16], au[16];
#pragma unroll
  for (int k = 0; k < 16; ++k) { ar[k] = 0.f; au[k] = 0.f; }
#pragma unroll
  for (int j = 0; j < 36; ++j) {
    float h = hs[j];
#pragma unroll
    for (int k = 0; k < 16; ++k) {
      ar[k] += h * s_rk[j * 16 + k];
      au[k] += h * s_uk[j * 16 + k];
    }
  }
  const float* sp = state + (size_t)b * 65536 + n;
#pragma unroll
  for (int k = 0; k < 16; ++k) {
    float r = 1.f / (1.f + __expf(-ar[k]));
    float uu = 1.f / (1.f + __expf(-au[k]));
    float prev = sp[(size_t)k * NNODE];
    s_x2[k * 264 + i] = f2b(r * prev);
    U[(size_t)(b * 16 + k) * NNODE + n] = uu;
  }
  __syncthreads();
  // flush 4096 bf16 (16 k x 256 n) to fragment layout: contiguous 8KB region.
  // global o = tl*512 + (qq*16+kk)*8 + jj ; element = (row b*16+kk, n nb*256 + tl*32+qq*8+jj)
  uint16_t* region = X2f + ((size_t)b * 128 + nb * 8) * 512;
#pragma unroll
  for (int rr = 0; rr < 2; ++rr) {
    int fid = rr * 256 + i;
    int kk = fid & 15, qq = (fid >> 4) & 3, tl = fid >> 6;
    uint4 v = *(const uint4*)&s_x2[kk * 264 + tl * 32 + qq * 8];
    *(uint4*)(region + (size_t)fid * 8) = v;
  }
}

// ---------- stage4: c = tanh([h;D3]*ck); z = u*prev + (1-u)*c ----------
// OUTPUT LAYOUT: z is (B, N, U) reshaped -> out[b*65536 + n*16 + k]
__global__ __launch_bounds__(256) void stage4(
    const uint16_t* __restrict__ P1, const uint16_t* __restrict__ P3,
    const float* __restrict__ U, const float* __restrict__ state,
    const float* __restrict__ ck, float* __restrict__ out) {
  constexpr size_t PS1 = (size_t)64 * 36 * NNODE;
  constexpr size_t PS3 = (size_t)64 * 32 * NNODE;
  __shared__ float s_ck[576];
  for (int i = threadIdx.x; i < 576; i += 256) s_ck[i] = ck[i];
  __syncthreads();
  int idx = blockIdx.x * 256 + threadIdx.x;
  int b = idx >> 12, n = idx & 4095;
  float hv[36];
  const uint16_t* p1 = P1 + (size_t)b * 36 * NNODE + n;
#pragma unroll
  for (int j = 0; j < 4; ++j)
    hv[j] = b2f(p1[(size_t)j * NNODE]) + b2f(p1[PS1 + (size_t)j * NNODE]);
  const uint16_t* p3 = P3 + (size_t)b * 32 * NNODE + n;
#pragma unroll
  for (int j = 0; j < 32; ++j)
    hv[4 + j] = b2f(p3[(size_t)j * NNODE]) + b2f(p3[PS3 + (size_t)j * NNODE]);
  float ac[16];
#pragma unroll
  for (int k = 0; k < 16; ++k) ac[k] = 0.f;
#pragma unroll
  for (int j = 0; j < 36; ++j) {
    float h = hv[j];
#pragma unroll
    for (int k = 0; k < 16; ++k) ac[k] += h * s_ck[j * 16 + k];
  }
  const float* sp = state + (size_t)b * 65536 + n;
  const float* up = U + (size_t)b * 16 * NNODE + n;
  float z[16];
#pragma unroll
  for (int k = 0; k < 16; ++k) {
    float e = __expf(2.f * ac[k]);
    float c = 1.f - 2.f / (e + 1.f);  // tanh, saturates at +/-inf
    float uu = up[(size_t)k * NNODE];
    float prev = sp[(size_t)k * NNODE];
    z[k] = uu * prev + (1.f - uu) * c;
  }
  float4* po = (float4*)(out + (size_t)b * 65536 + (size_t)n * 16);
#pragma unroll
  for (int k4 = 0; k4 < 4; ++k4)
    po[k4] = make_float4(z[k4 * 4], z[k4 * 4 + 1], z[k4 * 4 + 2], z[k4 * 4 + 3]);
}

extern "C" void kernel_launch(void* const* d_in, const int* in_sizes, int n_in,
                              void* d_out, int out_size, void* d_ws, size_t ws_size,
                              hipStream_t stream) {
  const float* inputs = (const float*)d_in[0];
  const float* state = (const float*)d_in[1];
  const float* s0 = (const float*)d_in[2];
  const float* s1 = (const float*)d_in[3];
  const float* rk = (const float*)d_in[4];
  const float* uk = (const float*)d_in[5];
  const float* ck = (const float*)d_in[6];
  float* out = (float*)d_out;
  char* ws = (char*)d_ws;

  // workspace layout (bytes); X2f aliases X1f (dead after gemm1)
  uint16_t* S0f = (uint16_t*)(ws);                  // 33,554,432
  uint16_t* S1f = (uint16_t*)(ws + 33554432);       // 33,554,432
  uint16_t* X1f = (uint16_t*)(ws + 67108864);       // 9,437,184   (1152 x 4096 bf16, frag)
  uint16_t* X2f = (uint16_t*)(ws + 67108864);       // 8,388,608   (aliases X1f, frag)
  uint16_t* P1 = (uint16_t*)(ws + 76546048);        // 2 x 18,874,368 (split-K partials)
  float* U = (float*)(ws + 114294784);              // 16,777,216
  uint16_t* P3 = (uint16_t*)(ws + 131072000);       // 2 x 16,777,216 (split-K partials)
  // total 164,626,432 bytes

  cvt_supports<<<dim3(256, 32, 2), 256, 0, stream>>>(s0, s1, S0f, S1f);
  pack_x1<<<dim3(72, 32), 256, 0, stream>>>(inputs, state, X1f);
  gemm_frag<1><<<dim3(32, 9, 2 * KSPLIT), 256, 0, stream>>>(X1f, S0f, S1f, P1);
  stage2<<<1024, 256, 0, stream>>>(P1, state, rk, uk, X2f, U);
  gemm_frag<3><<<dim3(32, 8, 2 * KSPLIT), 256, 0, stream>>>(X2f, S0f, S1f, P3);
  stage4<<<1024, 256, 0, stream>>>(P1, P3, U, state, ck, out);
}